// Round 7
// baseline (912.473 us; speedup 1.0000x reference)
//
#include <hip/hip_runtime.h>

#define NN 50000
#define MP 50048   // padded to 391*128
#define NH 4
#define NR 6
#define NE 300000
#define HD 256     // NH*DHD
#define SLOTS 32   // max degree read by agg; P(deg>32) ~ 1e-14
#define NG (NR * NN)
#define NB 512
#define BSZ ((NE + NB - 1) / NB)  // 586

typedef __attribute__((ext_vector_type(4))) float f32x4;
typedef __attribute__((ext_vector_type(8))) short bf16x8;

__device__ __forceinline__ short f2bf(float f) {
  unsigned u = __float_as_uint(f);
  unsigned r = (u + 0x7FFFu + ((u >> 16) & 1u)) >> 16;  // round-nearest-even
  return (short)r;
}
__device__ __forceinline__ float bf2f_lo(unsigned d) {
  return __uint_as_float(d << 16);
}
__device__ __forceinline__ float bf2f_hi(unsigned d) {
  return __uint_as_float(d & 0xffff0000u);
}

#define GLOAD_LDS16(g, l)                                                     \
  __builtin_amdgcn_global_load_lds(                                           \
      (const __attribute__((address_space(1))) void*)(g),                     \
      (__attribute__((address_space(3))) void*)(l), 16, 0, 0)

// ---------------- cast x -> bf16 ------------------------------------------
__global__ __launch_bounds__(256) void cast_x_kernel(
    const float* __restrict__ x, short* __restrict__ xb, int n4) {
  const int i = blockIdx.x * 256 + threadIdx.x;
  if (i >= n4) return;
  const float4 v = ((const float4*)x)[i];
  short4 o;
  o.x = f2bf(v.x); o.y = f2bf(v.y); o.z = f2bf(v.z); o.w = f2bf(v.w);
  ((short4*)xb)[i] = o;
}

// ---------------- cast + transpose W -> Wt[r][n][k] bf16 ------------------
__global__ __launch_bounds__(256) void cast_wt_kernel(
    const float* __restrict__ W, short* __restrict__ wt) {
  __shared__ float ts[32][33];
  const int bx = blockIdx.x;          // r * 64 + tile
  const int r = bx >> 6;
  const int tile = bx & 63;
  const int k0 = (tile >> 3) * 32;
  const int n0 = (tile & 7) * 32;
  const int t = threadIdx.x;
  const int col = t & 31;
  const int rr = t >> 5;  // 8 rows per pass
#pragma unroll
  for (int p = 0; p < 4; ++p) {
    const int row = p * 8 + rr;
    ts[row][col] = W[(size_t)r * 65536 + (k0 + row) * 256 + n0 + col];
  }
  __syncthreads();
#pragma unroll
  for (int p = 0; p < 4; ++p) {
    const int row = p * 8 + rr;  // n index
    wt[(size_t)r * 65536 + (n0 + row) * 256 + k0 + col] = f2bf(ts[col][row]);
  }
}

// ---------------- fused attn-projection matrices --------------------------
// wlwr[n][k], n = r*8 + h*2 + side (48 used, 128 padded with zeros):
// el = feat . attn_l = x @ (W attn_l): exact sum swap (validated R6).
__global__ __launch_bounds__(256) void wlwr_kernel(
    const float* __restrict__ W, const float* __restrict__ attn_l,
    const float* __restrict__ attn_r, short* __restrict__ wlwr) {
  const int idx = blockIdx.x * 256 + threadIdx.x;  // over 128*256
  if (idx >= 128 * 256) return;
  const int k = idx & 255;
  const int n = idx >> 8;
  float v = 0.f;
  if (n < 48) {
    const int r = n >> 3, h = (n >> 1) & 3, side = n & 1;
    const float* a = (side ? attn_r : attn_l) + r * 256 + h * 64;
    const float* wrow = W + (size_t)r * 65536 + (size_t)k * 256 + h * 64;
#pragma unroll 8
    for (int dh = 0; dh < 64; ++dh) v = fmaf(wrow[dh], a[dh], v);
  }
  wlwr[(size_t)n * 256 + k] = f2bf(v);
}

// ---------------- el/er skinny MFMA GEMM: xb @ wlwr^T ---------------------
__global__ __launch_bounds__(256) void eler_kernel(
    const short* __restrict__ xb, const short* __restrict__ wlwr,
    float* __restrict__ el_all, float* __restrict__ er_all) {
  __shared__ short As[128 * 64];
  __shared__ short Bs[128 * 64];
  const int t = threadIdx.x;
  const int lane = t & 63;
  const int w = t >> 6;
  const int wm = w & 1, wn = w >> 1;
  const int row0 = blockIdx.x * 128;

  f32x4 acc[4][4];
#pragma unroll
  for (int mi = 0; mi < 4; ++mi)
#pragma unroll
    for (int ni = 0; ni < 4; ++ni) {
      f32x4 z = {0.f, 0.f, 0.f, 0.f};
      acc[mi][ni] = z;
    }

  const short* ag[4];
  const short* bg[4];
  short* la[4];
  short* lb[4];
#pragma unroll
  for (int i = 0; i < 4; ++i) {
    const int c = t + 256 * i;
    const int row = c >> 3;
    const int sslot = (c & 7) ^ (row & 7);
    int ar = row0 + row; if (ar >= NN) ar = NN - 1;
    ag[i] = xb + (size_t)ar * 256 + sslot * 8;
    bg[i] = wlwr + (size_t)row * 256 + sslot * 8;
    la[i] = As + c * 8;
    lb[i] = Bs + c * 8;
  }

  const int ra = lane & 15;
  const int qg = lane >> 4;

  for (int k0 = 0; k0 < 256; k0 += 64) {
#pragma unroll
    for (int i = 0; i < 4; ++i) {
      GLOAD_LDS16(ag[i] + k0, la[i]);
      GLOAD_LDS16(bg[i] + k0, lb[i]);
    }
    __syncthreads();
#pragma unroll
    for (int kk = 0; kk < 2; ++kk) {
      bf16x8 af[4], bfr[4];
#pragma unroll
      for (int mi = 0; mi < 4; ++mi) {
        const int rw = wm * 64 + mi * 16 + ra;
        const int ch = (kk * 4 + qg) ^ (rw & 7);
        af[mi] = *(const bf16x8*)&As[rw * 64 + ch * 8];
      }
#pragma unroll
      for (int ni = 0; ni < 4; ++ni) {
        const int rw = wn * 64 + ni * 16 + ra;
        const int ch = (kk * 4 + qg) ^ (rw & 7);
        bfr[ni] = *(const bf16x8*)&Bs[rw * 64 + ch * 8];
      }
#pragma unroll
      for (int mi = 0; mi < 4; ++mi)
#pragma unroll
        for (int ni = 0; ni < 4; ++ni)
          acc[mi][ni] = __builtin_amdgcn_mfma_f32_16x16x32_bf16(
              af[mi], bfr[ni], acc[mi][ni], 0, 0, 0);
    }
    __syncthreads();
  }

#pragma unroll
  for (int mi = 0; mi < 4; ++mi) {
#pragma unroll
    for (int j = 0; j < 4; ++j) {
      const int row = row0 + wm * 64 + mi * 16 + (lane >> 4) * 4 + j;
      if (row >= NN) continue;
#pragma unroll
      for (int ni = 0; ni < 4; ++ni) {
        const int c = wn * 64 + ni * 16 + ra;
        if (c < 48) {
          const int r = c >> 3, h = (c >> 1) & 3, side = c & 1;
          float* dstp = (side ? er_all : el_all);
          dstp[((size_t)r * NN + row) * NH + h] = acc[mi][ni][j];
        }
      }
    }
  }
}

// ---------------- bf16 MFMA GEMM (all relations) -> featb -----------------
__global__ __launch_bounds__(256) void gemm_kernel(
    const short* __restrict__ xb,       // [NN][256] bf16
    const short* __restrict__ wt_all,   // [NR][256 n][256 k] bf16
    short* __restrict__ featb_all) {    // [NR][MP][256] bf16
  __shared__ short As[128 * 64];
  __shared__ short Bs[128 * 64];
  const int t = threadIdx.x;
  const int lane = t & 63;
  const int w = t >> 6;
  const int wm = w & 1, wn = w >> 1;
  const int row0 = blockIdx.x * 128;
  const int n0 = blockIdx.y * 128;
  const int r = blockIdx.z;
  const short* wt = wt_all + (size_t)r * 65536;
  short* featb = featb_all + (size_t)r * MP * 256;

  f32x4 acc[4][4];
#pragma unroll
  for (int mi = 0; mi < 4; ++mi)
#pragma unroll
    for (int ni = 0; ni < 4; ++ni) {
      f32x4 z = {0.f, 0.f, 0.f, 0.f};
      acc[mi][ni] = z;
    }

  const short* ag[4];
  const short* bg[4];
  short* la[4];
  short* lb[4];
#pragma unroll
  for (int i = 0; i < 4; ++i) {
    const int c = t + 256 * i;
    const int row = c >> 3;
    const int sslot = (c & 7) ^ (row & 7);
    int ar = row0 + row; if (ar >= NN) ar = NN - 1;
    ag[i] = xb + (size_t)ar * 256 + sslot * 8;
    bg[i] = wt + (size_t)(n0 + row) * 256 + sslot * 8;
    la[i] = As + c * 8;
    lb[i] = Bs + c * 8;
  }

  const int ra = lane & 15;
  const int qg = lane >> 4;

  for (int k0 = 0; k0 < 256; k0 += 64) {
#pragma unroll
    for (int i = 0; i < 4; ++i) {
      GLOAD_LDS16(ag[i] + k0, la[i]);
      GLOAD_LDS16(bg[i] + k0, lb[i]);
    }
    __syncthreads();
#pragma unroll
    for (int kk = 0; kk < 2; ++kk) {
      bf16x8 af[4], bfr[4];
#pragma unroll
      for (int mi = 0; mi < 4; ++mi) {
        const int rw = wm * 64 + mi * 16 + ra;
        const int ch = (kk * 4 + qg) ^ (rw & 7);
        af[mi] = *(const bf16x8*)&As[rw * 64 + ch * 8];
      }
#pragma unroll
      for (int ni = 0; ni < 4; ++ni) {
        const int rw = wn * 64 + ni * 16 + ra;
        const int ch = (kk * 4 + qg) ^ (rw & 7);
        bfr[ni] = *(const bf16x8*)&Bs[rw * 64 + ch * 8];
      }
#pragma unroll
      for (int mi = 0; mi < 4; ++mi)
#pragma unroll
        for (int ni = 0; ni < 4; ++ni)
          acc[mi][ni] = __builtin_amdgcn_mfma_f32_16x16x32_bf16(
              af[mi], bfr[ni], acc[mi][ni], 0, 0, 0);
    }
    __syncthreads();
  }

#pragma unroll
  for (int mi = 0; mi < 4; ++mi) {
#pragma unroll
    for (int j = 0; j < 4; ++j) {
      const int row = row0 + wm * 64 + mi * 16 + (lane >> 4) * 4 + j;
#pragma unroll
      for (int ni = 0; ni < 4; ++ni)
        featb[(size_t)row * 256 + n0 + wn * 64 + ni * 16 + ra] =
            f2bf(acc[mi][ni][j]);
    }
  }
}

// ---------------- CSR bucket build (replaces fixed-slot slots) ------------
// Old build scattered 1.8M u16 stores into a 19.2MB strided region
// (~1.8M 128B line-RMWs, the same random-access class that limits agg).
// CSR compacts the store target to ~8MB with 16B-aligned per-node lists
// (offsets padded to 8 u16s so agg's uint4 reads stay aligned).

// count: deg[g] = in-degree per (relation,node)
__global__ __launch_bounds__(256) void count_kernel(
    const int* __restrict__ dst, int* __restrict__ deg) {
  const int lo = blockIdx.x * BSZ;
  const int hi = (lo + BSZ < NE) ? lo + BSZ : NE;
  for (int r = 0; r < NR; ++r)
    for (int i = lo + threadIdx.x; i < hi; i += 256)
      atomicAdd(&deg[r * NN + dst[(size_t)r * NE + i]], 1);
}

// scan: off[g] = exclusive prefix sum of ceil(deg/8)*8 (u16 units).
// Single block, 8 elems/thread, wave-shfl scan + 16-wave LDS combine;
// 37 passes over 300K entries (~6us, latency not BW).
__global__ __launch_bounds__(1024) void scan_kernel(
    const int* __restrict__ deg, unsigned* __restrict__ off,
    unsigned* __restrict__ cursor) {
  __shared__ unsigned wsum[16];
  __shared__ unsigned carry_s;
  const int t = threadIdx.x;
  const int lane = t & 63;
  const int wv = t >> 6;
  if (t == 0) carry_s = 0;
  __syncthreads();
  for (int base = 0; base < NG; base += 8192) {
    unsigned v[8];
    unsigned tsum = 0;
    const int g0 = base + t * 8;
#pragma unroll
    for (int j = 0; j < 8; ++j) {
      const int g = g0 + j;
      const unsigned d = (g < NG) ? (unsigned)deg[g] : 0u;
      v[j] = (d + 7u) & ~7u;
      tsum += v[j];
    }
    unsigned sc = tsum;  // inclusive wave scan
#pragma unroll
    for (int s = 1; s < 64; s <<= 1) {
      const unsigned u = __shfl_up(sc, s, 64);
      if (lane >= s) sc += u;
    }
    if (lane == 63) wsum[wv] = sc;
    __syncthreads();
    if (wv == 0 && lane < 16) {
      unsigned ws = wsum[lane];
#pragma unroll
      for (int s = 1; s < 16; s <<= 1) {
        const unsigned u = __shfl_up(ws, s, 64);
        if (lane >= s) ws += u;
      }
      wsum[lane] = ws;  // inclusive
    }
    __syncthreads();
    const unsigned wbase = (wv == 0) ? 0u : wsum[wv - 1];
    unsigned run = carry_s + wbase + (sc - tsum);  // exclusive start
#pragma unroll
    for (int j = 0; j < 8; ++j) {
      const int g = g0 + j;
      if (g < NG) { off[g] = run; cursor[g] = run; }
      run += v[j];
    }
    __syncthreads();
    if (t == 0) carry_s += wsum[15];
    __syncthreads();
  }
}

// fill: csr[cursor[g]++] = src  (positions unique via atomic)
__global__ __launch_bounds__(256) void fill_kernel(
    const int* __restrict__ src, const int* __restrict__ dst,
    unsigned* __restrict__ cursor, unsigned short* __restrict__ csr) {
  const int lo = blockIdx.x * BSZ;
  const int hi = (lo + BSZ < NE) ? lo + BSZ : NE;
  for (int r = 0; r < NR; ++r) {
    for (int i = lo + threadIdx.x; i < hi; i += 256) {
      const int s = src[(size_t)r * NE + i];
      const int d = dst[(size_t)r * NE + i];
      const unsigned pos = atomicAdd(&cursor[r * NN + d], 1u);
      csr[pos] = (unsigned short)s;
    }
  }
}

// ---------------- fused all-relation aggregation, SGPR slot list ----------
// CONTROL for the gather path (163us / 563MB across 4 schedule variants).
// Only the metadata source changed: slot list now read from the compact
// 16B-aligned CSR (csr + off[g]) instead of the strided slots array.
__global__ __launch_bounds__(256) void agg_kernel(
    const short* __restrict__ featb_all, const float* __restrict__ el_all,
    const float* __restrict__ er_all, const int* __restrict__ deg,
    const unsigned* __restrict__ off, const unsigned short* __restrict__ csr,
    const float* __restrict__ bias, float* __restrict__ out) {
  const int wid = (blockIdx.x * 256 + threadIdx.x) >> 6;  // node (wave-unif)
  const int lane = threadIdx.x & 63;
  if (wid >= NN) return;
  const int h = lane >> 4;   // 16 lanes per head (64 cols / 4 per lane)
  const int c0 = lane * 4;   // this lane's 4 columns

  float oacc[4] = {0.f, 0.f, 0.f, 0.f};
  const int wid_u = __builtin_amdgcn_readfirstlane(wid);

  const int g_first = (NR - 1) * NN + wid_u;
  const uint4* spf = (const uint4*)(csr + off[g_first]);  // 16B-aligned
  uint4 sq0 = spf[0], sq1 = spf[1], sq2 = spf[2], sq3 = spf[3];
  int dgv = deg[g_first];
  float erv = er_all[(size_t)g_first * NH + h];

  for (int r = NR - 1; r >= 0; --r) {
    const int dg0 = __builtin_amdgcn_readfirstlane(dgv);
    const int dg = dg0 > SLOTS ? SLOTS : dg0;
    unsigned sdv[16];
    sdv[0]  = __builtin_amdgcn_readfirstlane(sq0.x);
    sdv[1]  = __builtin_amdgcn_readfirstlane(sq0.y);
    sdv[2]  = __builtin_amdgcn_readfirstlane(sq0.z);
    sdv[3]  = __builtin_amdgcn_readfirstlane(sq0.w);
    sdv[4]  = __builtin_amdgcn_readfirstlane(sq1.x);
    sdv[5]  = __builtin_amdgcn_readfirstlane(sq1.y);
    sdv[6]  = __builtin_amdgcn_readfirstlane(sq1.z);
    sdv[7]  = __builtin_amdgcn_readfirstlane(sq1.w);
    sdv[8]  = __builtin_amdgcn_readfirstlane(sq2.x);
    sdv[9]  = __builtin_amdgcn_readfirstlane(sq2.y);
    sdv[10] = __builtin_amdgcn_readfirstlane(sq2.z);
    sdv[11] = __builtin_amdgcn_readfirstlane(sq2.w);
    sdv[12] = __builtin_amdgcn_readfirstlane(sq3.x);
    sdv[13] = __builtin_amdgcn_readfirstlane(sq3.y);
    sdv[14] = __builtin_amdgcn_readfirstlane(sq3.z);
    sdv[15] = __builtin_amdgcn_readfirstlane(sq3.w);
    const float er_nh = erv;

    if (r > 0) {
      const int g2 = (r - 1) * NN + wid_u;
      const uint4* sp2 = (const uint4*)(csr + off[g2]);
      sq0 = sp2[0]; sq1 = sp2[1]; sq2 = sp2[2]; sq3 = sp2[3];
      dgv = deg[g2];
      erv = er_all[(size_t)g2 * NH + h];
    }

    const float* elr = el_all + (size_t)r * NN * NH;
    const short* fb = featb_all + (size_t)r * MP * 256;

    float z = 0.f;
    float acc[4] = {0.f, 0.f, 0.f, 0.f};

#pragma unroll
    for (int j0 = 0; j0 < SLOTS; j0 += 8) {
      if (j0 >= dg) break;  // uniform (dg is SGPR)
      float pv[8];
      uint2 rw[8];
#pragma unroll
      for (int k = 0; k < 8; ++k) {
        const int e = j0 + k;  // compile-time after unroll
        int s = (int)((e & 1) ? (sdv[e >> 1] >> 16) : (sdv[e >> 1] & 0xffffu));
        const bool v = e < dg;           // uniform
        s = v ? s : 0;                   // row 0 stays hot
        rw[k] = *(const uint2*)(fb + (size_t)s * 256 + c0);  // SGPR base+voff
        float ev = elr[s * NH + h] + er_nh;
        ev = fmaxf(ev, 0.2f * ev);       // leaky_relu(0.2)
        pv[k] = v ? __expf(ev) : 0.f;
      }
#pragma unroll
      for (int k = 0; k < 8; ++k) {
        z += pv[k];
        acc[0] = fmaf(pv[k], bf2f_lo(rw[k].x), acc[0]);
        acc[1] = fmaf(pv[k], bf2f_hi(rw[k].x), acc[1]);
        acc[2] = fmaf(pv[k], bf2f_lo(rw[k].y), acc[2]);
        acc[3] = fmaf(pv[k], bf2f_hi(rw[k].y), acc[3]);
      }
    }

    const float inv = 1.f / fmaxf(z, 1e-9f);
    const float4 bv = *(const float4*)(bias + r * HD + c0);
    oacc[0] += fmaxf(fmaf(acc[0], inv, bv.x), 0.f);
    oacc[1] += fmaxf(fmaf(acc[1], inv, bv.y), 0.f);
    oacc[2] += fmaxf(fmaf(acc[2], inv, bv.z), 0.f);
    oacc[3] += fmaxf(fmaf(acc[3], inv, bv.w), 0.f);
  }

  float4 o4 = {oacc[0], oacc[1], oacc[2], oacc[3]};
  *(float4*)(out + (size_t)wid * 256 + c0) = o4;  // full-wave 1KB store
}

// ---------------------------------------------------------------------------
extern "C" void kernel_launch(void* const* d_in, const int* in_sizes, int n_in,
                              void* d_out, int out_size, void* d_ws,
                              size_t ws_size, hipStream_t stream) {
  const float* x      = (const float*)d_in[0];
  const float* W      = (const float*)d_in[1];
  const float* attn_l = (const float*)d_in[2];
  const float* attn_r = (const float*)d_in[3];
  const float* bias   = (const float*)d_in[4];
  const int*   src    = (const int*)d_in[5];   // int32 per harness contract
  const int*   dst    = (const int*)d_in[6];
  float* out = (float*)d_out;

  char* p = (char*)d_ws;
  auto alloc = [&](size_t bytes) {
    char* r = p;
    p += (bytes + 255) & ~(size_t)255;
    return r;
  };
  short* xb    = (short*)alloc((size_t)NN * HD * 2);            // 25.6 MB
  short* wt    = (short*)alloc((size_t)NR * 256 * 256 * 2);     // 0.79 MB
  short* wlwr  = (short*)alloc((size_t)128 * 256 * 2);          // 64 KB
  short* featb = (short*)alloc((size_t)NR * MP * 256 * 2);      // 153.7 MB
  float* el    = (float*)alloc((size_t)NR * NN * NH * 4);       // 4.8 MB
  float* er    = (float*)alloc((size_t)NR * NN * NH * 4);       // 4.8 MB
  int*   deg   = (int*)alloc((size_t)NG * 4);                   // 1.2 MB
  unsigned* off    = (unsigned*)alloc((size_t)NG * 4);          // 1.2 MB
  unsigned* cursor = (unsigned*)alloc((size_t)NG * 4);          // 1.2 MB
  unsigned short* csr =
      (unsigned short*)alloc(((size_t)NR * NE + (size_t)NG * 8 + 64) * 2);

  hipMemsetAsync(deg, 0, (size_t)NG * 4, stream);

  cast_x_kernel<<<(NN * HD / 4 + 255) / 256, 256, 0, stream>>>(x, xb,
                                                               NN * HD / 4);
  cast_wt_kernel<<<NR * 64, 256, 0, stream>>>(W, wt);
  wlwr_kernel<<<128, 256, 0, stream>>>(W, attn_l, attn_r, wlwr);
  count_kernel<<<NB, 256, 0, stream>>>(dst, deg);
  scan_kernel<<<1, 1024, 0, stream>>>(deg, off, cursor);
  fill_kernel<<<NB, 256, 0, stream>>>(src, dst, cursor, csr);
  eler_kernel<<<MP / 128, 256, 0, stream>>>(xb, wlwr, el, er);
  gemm_kernel<<<dim3(MP / 128, 2, NR), 256, 0, stream>>>(xb, wt, featb);
  agg_kernel<<<(NN * 64) / 256, 256, 0, stream>>>(featb, el, er, deg, off,
                                                  csr, bias, out);
}

// Round 8
// 497.442 us; speedup vs baseline: 1.8343x; 1.8343x over previous
//
#include <hip/hip_runtime.h>

#define NN 50000
#define MP 50048   // padded to 391*128
#define NH 4
#define NR 6
#define NE 300000
#define HD 256     // NH*DHD
#define SLOTS 32   // max degree per (relation,node); P(deg>32) ~ 1e-14
#define NB 512
#define BSZ ((NE + NB - 1) / NB)  // 586

typedef __attribute__((ext_vector_type(4))) float f32x4;
typedef __attribute__((ext_vector_type(8))) short bf16x8;

__device__ __forceinline__ short f2bf(float f) {
  unsigned u = __float_as_uint(f);
  unsigned r = (u + 0x7FFFu + ((u >> 16) & 1u)) >> 16;  // round-nearest-even
  return (short)r;
}
__device__ __forceinline__ float bf2f_lo(unsigned d) {
  return __uint_as_float(d << 16);
}
__device__ __forceinline__ float bf2f_hi(unsigned d) {
  return __uint_as_float(d & 0xffff0000u);
}

#define GLOAD_LDS16(g, l)                                                     \
  __builtin_amdgcn_global_load_lds(                                           \
      (const __attribute__((address_space(1))) void*)(g),                     \
      (__attribute__((address_space(3))) void*)(l), 16, 0, 0)

// ---------------- cast x -> bf16 ------------------------------------------
__global__ __launch_bounds__(256) void cast_x_kernel(
    const float* __restrict__ x, short* __restrict__ xb, int n4) {
  const int i = blockIdx.x * 256 + threadIdx.x;
  if (i >= n4) return;
  const float4 v = ((const float4*)x)[i];
  short4 o;
  o.x = f2bf(v.x); o.y = f2bf(v.y); o.z = f2bf(v.z); o.w = f2bf(v.w);
  ((short4*)xb)[i] = o;
}

// ---------------- cast + transpose W -> Wt[r][n][k] bf16 ------------------
__global__ __launch_bounds__(256) void cast_wt_kernel(
    const float* __restrict__ W, short* __restrict__ wt) {
  __shared__ float ts[32][33];
  const int bx = blockIdx.x;          // r * 64 + tile
  const int r = bx >> 6;
  const int tile = bx & 63;
  const int k0 = (tile >> 3) * 32;
  const int n0 = (tile & 7) * 32;
  const int t = threadIdx.x;
  const int col = t & 31;
  const int rr = t >> 5;  // 8 rows per pass
#pragma unroll
  for (int p = 0; p < 4; ++p) {
    const int row = p * 8 + rr;
    ts[row][col] = W[(size_t)r * 65536 + (k0 + row) * 256 + n0 + col];
  }
  __syncthreads();
#pragma unroll
  for (int p = 0; p < 4; ++p) {
    const int row = p * 8 + rr;  // n index
    wt[(size_t)r * 65536 + (n0 + row) * 256 + k0 + col] = f2bf(ts[col][row]);
  }
}

// ---------------- fused attn-projection matrices --------------------------
// wlwr[n][k], n = r*8 + h*2 + side (48 used, 128 padded with zeros):
// el = feat . attn_l = x @ (W attn_l): exact sum swap (validated R6).
__global__ __launch_bounds__(256) void wlwr_kernel(
    const float* __restrict__ W, const float* __restrict__ attn_l,
    const float* __restrict__ attn_r, short* __restrict__ wlwr) {
  const int idx = blockIdx.x * 256 + threadIdx.x;  // over 128*256
  if (idx >= 128 * 256) return;
  const int k = idx & 255;
  const int n = idx >> 8;
  float v = 0.f;
  if (n < 48) {
    const int r = n >> 3, h = (n >> 1) & 3, side = n & 1;
    const float* a = (side ? attn_r : attn_l) + r * 256 + h * 64;
    const float* wrow = W + (size_t)r * 65536 + (size_t)k * 256 + h * 64;
#pragma unroll 8
    for (int dh = 0; dh < 64; ++dh) v = fmaf(wrow[dh], a[dh], v);
  }
  wlwr[(size_t)n * 256 + k] = f2bf(v);
}

// ---------------- el/er skinny MFMA GEMM: xb @ wlwr^T ---------------------
__global__ __launch_bounds__(256) void eler_kernel(
    const short* __restrict__ xb, const short* __restrict__ wlwr,
    float* __restrict__ el_all, float* __restrict__ er_all) {
  __shared__ short As[128 * 64];
  __shared__ short Bs[128 * 64];
  const int t = threadIdx.x;
  const int lane = t & 63;
  const int w = t >> 6;
  const int wm = w & 1, wn = w >> 1;
  const int row0 = blockIdx.x * 128;

  f32x4 acc[4][4];
#pragma unroll
  for (int mi = 0; mi < 4; ++mi)
#pragma unroll
    for (int ni = 0; ni < 4; ++ni) {
      f32x4 z = {0.f, 0.f, 0.f, 0.f};
      acc[mi][ni] = z;
    }

  const short* ag[4];
  const short* bg[4];
  short* la[4];
  short* lb[4];
#pragma unroll
  for (int i = 0; i < 4; ++i) {
    const int c = t + 256 * i;
    const int row = c >> 3;
    const int sslot = (c & 7) ^ (row & 7);
    int ar = row0 + row; if (ar >= NN) ar = NN - 1;
    ag[i] = xb + (size_t)ar * 256 + sslot * 8;
    bg[i] = wlwr + (size_t)row * 256 + sslot * 8;
    la[i] = As + c * 8;
    lb[i] = Bs + c * 8;
  }

  const int ra = lane & 15;
  const int qg = lane >> 4;

  for (int k0 = 0; k0 < 256; k0 += 64) {
#pragma unroll
    for (int i = 0; i < 4; ++i) {
      GLOAD_LDS16(ag[i] + k0, la[i]);
      GLOAD_LDS16(bg[i] + k0, lb[i]);
    }
    __syncthreads();
#pragma unroll
    for (int kk = 0; kk < 2; ++kk) {
      bf16x8 af[4], bfr[4];
#pragma unroll
      for (int mi = 0; mi < 4; ++mi) {
        const int rw = wm * 64 + mi * 16 + ra;
        const int ch = (kk * 4 + qg) ^ (rw & 7);
        af[mi] = *(const bf16x8*)&As[rw * 64 + ch * 8];
      }
#pragma unroll
      for (int ni = 0; ni < 4; ++ni) {
        const int rw = wn * 64 + ni * 16 + ra;
        const int ch = (kk * 4 + qg) ^ (rw & 7);
        bfr[ni] = *(const bf16x8*)&Bs[rw * 64 + ch * 8];
      }
#pragma unroll
      for (int mi = 0; mi < 4; ++mi)
#pragma unroll
        for (int ni = 0; ni < 4; ++ni)
          acc[mi][ni] = __builtin_amdgcn_mfma_f32_16x16x32_bf16(
              af[mi], bfr[ni], acc[mi][ni], 0, 0, 0);
    }
    __syncthreads();
  }

#pragma unroll
  for (int mi = 0; mi < 4; ++mi) {
#pragma unroll
    for (int j = 0; j < 4; ++j) {
      const int row = row0 + wm * 64 + mi * 16 + (lane >> 4) * 4 + j;
      if (row >= NN) continue;
#pragma unroll
      for (int ni = 0; ni < 4; ++ni) {
        const int c = wn * 64 + ni * 16 + ra;
        if (c < 48) {
          const int r = c >> 3, h = (c >> 1) & 3, side = c & 1;
          float* dstp = (side ? er_all : el_all);
          dstp[((size_t)r * NN + row) * NH + h] = acc[mi][ni][j];
        }
      }
    }
  }
}

// ---------------- A-resident bf16 MFMA GEMM -> featb ----------------------
// Full 128x256 A tile staged ONCE per block (64 KB LDS); relation loop
// inside stages only B (16 KB/K-step). Steady-state staged bytes per
// barrier halve (m233: stage+vmcnt+barrier dominates 2-phase loops) and
// A staging issues drop 6x. A swizzle widens to slot^(row&31) (5-bit
// involution, both-sides per rule #21); 16-lane read groups spread over
// 8 banks x 2-way = free (m136). B path byte-identical to R4-verified.
// LDS 80 KB -> 2 blocks/CU.
__global__ __launch_bounds__(256) void gemm_kernel(
    const short* __restrict__ xb,       // [NN][256] bf16
    const short* __restrict__ wt_all,   // [NR][256 n][256 k] bf16
    short* __restrict__ featb_all) {    // [NR][MP][256] bf16
  __shared__ short As[128 * 256];  // 64 KB, full-K A tile
  __shared__ short Bs[128 * 64];   // 16 KB, per-K-step B tile
  const int t = threadIdx.x;
  const int lane = t & 63;
  const int w = t >> 6;
  const int wm = w & 1, wn = w >> 1;
  const int row0 = blockIdx.x * 128;
  const int n0 = blockIdx.y * 128;

  // stage full A once: 4096 16B chunks, 16/thread, linear LDS dest,
  // pre-swizzled global source (rule #21 both-sides)
#pragma unroll
  for (int i = 0; i < 16; ++i) {
    const int c = t + 256 * i;
    const int row = c >> 5;                    // 0..127
    const int slot = (c & 31) ^ (row & 31);    // 5-bit involution
    int ar = row0 + row; if (ar >= NN) ar = NN - 1;
    GLOAD_LDS16(xb + (size_t)ar * 256 + slot * 8, As + c * 8);
  }

  // B staging addresses (rebased per relation/K-step)
  size_t bsrc[4];
  short* bdst[4];
#pragma unroll
  for (int i = 0; i < 4; ++i) {
    const int c = t + 256 * i;
    const int row = c >> 3;                    // n-row 0..127
    const int slot = (c & 7) ^ (row & 7);
    bsrc[i] = (size_t)(n0 + row) * 256 + slot * 8;
    bdst[i] = Bs + c * 8;
  }

  const int ra = lane & 15;
  const int qg = lane >> 4;

  for (int r = 0; r < NR; ++r) {
    const short* wtr = wt_all + (size_t)r * 65536;
    f32x4 acc[4][4];
#pragma unroll
    for (int mi = 0; mi < 4; ++mi)
#pragma unroll
      for (int ni = 0; ni < 4; ++ni) {
        f32x4 z = {0.f, 0.f, 0.f, 0.f};
        acc[mi][ni] = z;
      }

    for (int s = 0; s < 4; ++s) {
#pragma unroll
      for (int i = 0; i < 4; ++i)
        GLOAD_LDS16(wtr + bsrc[i] + s * 64, bdst[i]);
      __syncthreads();  // drains A loads too on first pass
#pragma unroll
      for (int kk = 0; kk < 2; ++kk) {
        bf16x8 af[4], bfr[4];
#pragma unroll
        for (int mi = 0; mi < 4; ++mi) {
          const int rw = wm * 64 + mi * 16 + ra;
          const int sl = (s * 8 + kk * 4 + qg) ^ (rw & 31);
          af[mi] = *(const bf16x8*)&As[rw * 256 + sl * 8];
        }
#pragma unroll
        for (int ni = 0; ni < 4; ++ni) {
          const int rwb = wn * 64 + ni * 16 + ra;
          const int ch = (kk * 4 + qg) ^ (rwb & 7);
          bfr[ni] = *(const bf16x8*)&Bs[rwb * 64 + ch * 8];
        }
#pragma unroll
        for (int mi = 0; mi < 4; ++mi)
#pragma unroll
          for (int ni = 0; ni < 4; ++ni)
            acc[mi][ni] = __builtin_amdgcn_mfma_f32_16x16x32_bf16(
                af[mi], bfr[ni], acc[mi][ni], 0, 0, 0);
      }
      __syncthreads();
    }

    short* featb = featb_all + (size_t)r * MP * 256;
#pragma unroll
    for (int mi = 0; mi < 4; ++mi) {
#pragma unroll
      for (int j = 0; j < 4; ++j) {
        const int row = row0 + wm * 64 + mi * 16 + qg * 4 + j;
#pragma unroll
        for (int ni = 0; ni < 4; ++ni)
          featb[(size_t)row * 256 + n0 + wn * 64 + ni * 16 + ra] =
              f2bf(acc[mi][ni][j]);
      }
    }
  }
}

// ---------------- single-pass fixed-slot bucket build ---------------------
// R6-verified (CSR experiment R7: scan 404us single-block + count/fill
// costing build+50 -> reverted).
__global__ __launch_bounds__(256) void build_kernel(
    const int* __restrict__ src, const int* __restrict__ dst,
    int* __restrict__ deg, unsigned short* __restrict__ slots) {
  const int lo = blockIdx.x * BSZ;
  const int hi = (lo + BSZ < NE) ? lo + BSZ : NE;
  for (int r = 0; r < NR; ++r) {
    for (int i = lo + threadIdx.x; i < hi; i += 256) {
      const int s = src[(size_t)r * NE + i];
      const int d = dst[(size_t)r * NE + i];
      const int g = r * NN + d;
      const int sl = atomicAdd(&deg[g], 1);
      if (sl < SLOTS)
        slots[(size_t)g * SLOTS + sl] = (unsigned short)s;
    }
  }
}

// ---------------- fused all-relation aggregation, SGPR slot list ----------
// CONTROL: byte-identical to the R6-verified agg (random-gather BW-bound,
// ~163us / 563MB across 4 schedule variants).
__global__ __launch_bounds__(256) void agg_kernel(
    const short* __restrict__ featb_all, const float* __restrict__ el_all,
    const float* __restrict__ er_all, const int* __restrict__ deg,
    const unsigned short* __restrict__ slots, const float* __restrict__ bias,
    float* __restrict__ out) {
  const int wid = (blockIdx.x * 256 + threadIdx.x) >> 6;  // node (wave-unif)
  const int lane = threadIdx.x & 63;
  if (wid >= NN) return;
  const int h = lane >> 4;   // 16 lanes per head (64 cols / 4 per lane)
  const int c0 = lane * 4;   // this lane's 4 columns

  float oacc[4] = {0.f, 0.f, 0.f, 0.f};
  const int wid_u = __builtin_amdgcn_readfirstlane(wid);

  const int g_first = (NR - 1) * NN + wid_u;
  const uint4* spf = (const uint4*)(slots + (size_t)g_first * SLOTS);
  uint4 sq0 = spf[0], sq1 = spf[1], sq2 = spf[2], sq3 = spf[3];
  int dgv = deg[g_first];
  float erv = er_all[(size_t)g_first * NH + h];

  for (int r = NR - 1; r >= 0; --r) {
    const int dg0 = __builtin_amdgcn_readfirstlane(dgv);
    const int dg = dg0 > SLOTS ? SLOTS : dg0;
    unsigned sdv[16];
    sdv[0]  = __builtin_amdgcn_readfirstlane(sq0.x);
    sdv[1]  = __builtin_amdgcn_readfirstlane(sq0.y);
    sdv[2]  = __builtin_amdgcn_readfirstlane(sq0.z);
    sdv[3]  = __builtin_amdgcn_readfirstlane(sq0.w);
    sdv[4]  = __builtin_amdgcn_readfirstlane(sq1.x);
    sdv[5]  = __builtin_amdgcn_readfirstlane(sq1.y);
    sdv[6]  = __builtin_amdgcn_readfirstlane(sq1.z);
    sdv[7]  = __builtin_amdgcn_readfirstlane(sq1.w);
    sdv[8]  = __builtin_amdgcn_readfirstlane(sq2.x);
    sdv[9]  = __builtin_amdgcn_readfirstlane(sq2.y);
    sdv[10] = __builtin_amdgcn_readfirstlane(sq2.z);
    sdv[11] = __builtin_amdgcn_readfirstlane(sq2.w);
    sdv[12] = __builtin_amdgcn_readfirstlane(sq3.x);
    sdv[13] = __builtin_amdgcn_readfirstlane(sq3.y);
    sdv[14] = __builtin_amdgcn_readfirstlane(sq3.z);
    sdv[15] = __builtin_amdgcn_readfirstlane(sq3.w);
    const float er_nh = erv;

    if (r > 0) {
      const int g2 = (r - 1) * NN + wid_u;
      const uint4* sp2 = (const uint4*)(slots + (size_t)g2 * SLOTS);
      sq0 = sp2[0]; sq1 = sp2[1]; sq2 = sp2[2]; sq3 = sp2[3];
      dgv = deg[g2];
      erv = er_all[(size_t)g2 * NH + h];
    }

    const float* elr = el_all + (size_t)r * NN * NH;
    const short* fb = featb_all + (size_t)r * MP * 256;

    float z = 0.f;
    float acc[4] = {0.f, 0.f, 0.f, 0.f};

#pragma unroll
    for (int j0 = 0; j0 < SLOTS; j0 += 8) {
      if (j0 >= dg) break;  // uniform (dg is SGPR)
      float pv[8];
      uint2 rw[8];
#pragma unroll
      for (int k = 0; k < 8; ++k) {
        const int e = j0 + k;  // compile-time after unroll
        int s = (int)((e & 1) ? (sdv[e >> 1] >> 16) : (sdv[e >> 1] & 0xffffu));
        const bool v = e < dg;           // uniform
        s = v ? s : 0;                   // row 0 stays hot
        rw[k] = *(const uint2*)(fb + (size_t)s * 256 + c0);  // SGPR base+voff
        float ev = elr[s * NH + h] + er_nh;
        ev = fmaxf(ev, 0.2f * ev);       // leaky_relu(0.2)
        pv[k] = v ? __expf(ev) : 0.f;
      }
#pragma unroll
      for (int k = 0; k < 8; ++k) {
        z += pv[k];
        acc[0] = fmaf(pv[k], bf2f_lo(rw[k].x), acc[0]);
        acc[1] = fmaf(pv[k], bf2f_hi(rw[k].x), acc[1]);
        acc[2] = fmaf(pv[k], bf2f_lo(rw[k].y), acc[2]);
        acc[3] = fmaf(pv[k], bf2f_hi(rw[k].y), acc[3]);
      }
    }

    const float inv = 1.f / fmaxf(z, 1e-9f);
    const float4 bv = *(const float4*)(bias + r * HD + c0);
    oacc[0] += fmaxf(fmaf(acc[0], inv, bv.x), 0.f);
    oacc[1] += fmaxf(fmaf(acc[1], inv, bv.y), 0.f);
    oacc[2] += fmaxf(fmaf(acc[2], inv, bv.z), 0.f);
    oacc[3] += fmaxf(fmaf(acc[3], inv, bv.w), 0.f);
  }

  float4 o4 = {oacc[0], oacc[1], oacc[2], oacc[3]};
  *(float4*)(out + (size_t)wid * 256 + c0) = o4;  // full-wave 1KB store
}

// ---------------------------------------------------------------------------
extern "C" void kernel_launch(void* const* d_in, const int* in_sizes, int n_in,
                              void* d_out, int out_size, void* d_ws,
                              size_t ws_size, hipStream_t stream) {
  const float* x      = (const float*)d_in[0];
  const float* W      = (const float*)d_in[1];
  const float* attn_l = (const float*)d_in[2];
  const float* attn_r = (const float*)d_in[3];
  const float* bias   = (const float*)d_in[4];
  const int*   src    = (const int*)d_in[5];   // int32 per harness contract
  const int*   dst    = (const int*)d_in[6];
  float* out = (float*)d_out;

  char* p = (char*)d_ws;
  auto alloc = [&](size_t bytes) {
    char* r = p;
    p += (bytes + 255) & ~(size_t)255;
    return r;
  };
  short* xb    = (short*)alloc((size_t)NN * HD * 2);            // 25.6 MB
  short* wt    = (short*)alloc((size_t)NR * 256 * 256 * 2);     // 0.79 MB
  short* wlwr  = (short*)alloc((size_t)128 * 256 * 2);          // 64 KB
  short* featb = (short*)alloc((size_t)NR * MP * 256 * 2);      // 153.7 MB
  float* el    = (float*)alloc((size_t)NR * NN * NH * 4);       // 4.8 MB
  float* er    = (float*)alloc((size_t)NR * NN * NH * 4);       // 4.8 MB
  int*   deg   = (int*)alloc((size_t)NR * NN * 4);              // 1.2 MB
  unsigned short* slots =
      (unsigned short*)alloc((size_t)NR * NN * SLOTS * 2);      // 19.2 MB

  hipMemsetAsync(deg, 0, (size_t)NR * NN * 4, stream);

  cast_x_kernel<<<(NN * HD / 4 + 255) / 256, 256, 0, stream>>>(x, xb,
                                                               NN * HD / 4);
  cast_wt_kernel<<<NR * 64, 256, 0, stream>>>(W, wt);
  wlwr_kernel<<<128, 256, 0, stream>>>(W, attn_l, attn_r, wlwr);
  build_kernel<<<NB, 256, 0, stream>>>(src, dst, deg, slots);
  eler_kernel<<<MP / 128, 256, 0, stream>>>(xb, wlwr, el, er);
  gemm_kernel<<<dim3(MP / 128, 2), 256, 0, stream>>>(xb, wt, featb);
  agg_kernel<<<(NN * 64) / 256, 256, 0, stream>>>(featb, el, er, deg, slots,
                                                  bias, out);
}

// Round 9
// 449.009 us; speedup vs baseline: 2.0322x; 1.1079x over previous
//
#include <hip/hip_runtime.h>

#define NN 50000
#define MP 50048   // padded to 391*128
#define NH 4
#define NR 6
#define NE 300000
#define HD 256     // NH*DHD
#define SLOTS 32   // max degree per (relation,node); P(deg>32) ~ 1e-14
#define NB 512
#define BSZ ((NE + NB - 1) / NB)  // 586

typedef __attribute__((ext_vector_type(4))) float f32x4;
typedef __attribute__((ext_vector_type(8))) short bf16x8;

__device__ __forceinline__ short f2bf(float f) {
  unsigned u = __float_as_uint(f);
  unsigned r = (u + 0x7FFFu + ((u >> 16) & 1u)) >> 16;  // round-nearest-even
  return (short)r;
}
__device__ __forceinline__ float bf2f_lo(unsigned d) {
  return __uint_as_float(d << 16);
}
__device__ __forceinline__ float bf2f_hi(unsigned d) {
  return __uint_as_float(d & 0xffff0000u);
}

#define GLOAD_LDS16(g, l)                                                     \
  __builtin_amdgcn_global_load_lds(                                           \
      (const __attribute__((address_space(1))) void*)(g),                     \
      (__attribute__((address_space(3))) void*)(l), 16, 0, 0)

// ---------------- fused prep: cast_x | cast_wt | wlwr | build -------------
// The four prep tasks are mutually independent; serial launches cost the
// SUM of their times, one block-partitioned launch costs the MAX (build).
// blocks [0,1024): cast_x grid-stride; [1024,1408): cast_wt 32x32 tiles;
// [1408,1536): wlwr; [1536,2048): build chunks. Branch is block-uniform.
__global__ __launch_bounds__(256) void prep_kernel(
    const float* __restrict__ x, short* __restrict__ xb,
    const float* __restrict__ W, short* __restrict__ wt,
    const float* __restrict__ attn_l, const float* __restrict__ attn_r,
    short* __restrict__ wlwr, const int* __restrict__ src,
    const int* __restrict__ dst, int* __restrict__ deg,
    unsigned short* __restrict__ slots) {
  __shared__ float ts[32][33];
  const int bid = blockIdx.x;
  const int t = threadIdx.x;

  if (bid < 1024) {
    // ---- cast_x: x (f32) -> xb (bf16), 3.2M float4, grid-stride ----
    for (int i = bid * 256 + t; i < NN * HD / 4; i += 1024 * 256) {
      const float4 v = ((const float4*)x)[i];
      short4 o;
      o.x = f2bf(v.x); o.y = f2bf(v.y); o.z = f2bf(v.z); o.w = f2bf(v.w);
      ((short4*)xb)[i] = o;
    }
  } else if (bid < 1408) {
    // ---- cast_wt: LDS 32x32 tile transpose, coalesced both sides ----
    const int bx = bid - 1024;          // r * 64 + tile
    const int r = bx >> 6;
    const int tile = bx & 63;
    const int k0 = (tile >> 3) * 32;
    const int n0 = (tile & 7) * 32;
    const int col = t & 31;
    const int rr = t >> 5;  // 8 rows per pass
#pragma unroll
    for (int p = 0; p < 4; ++p) {
      const int row = p * 8 + rr;
      ts[row][col] = W[(size_t)r * 65536 + (k0 + row) * 256 + n0 + col];
    }
    __syncthreads();
#pragma unroll
    for (int p = 0; p < 4; ++p) {
      const int row = p * 8 + rr;  // n index
      wt[(size_t)r * 65536 + (n0 + row) * 256 + k0 + col] =
          f2bf(ts[col][row]);
    }
  } else if (bid < 1536) {
    // ---- wlwr[n][k]: fused attn-projection (exact sum swap, R6) ----
    const int idx = (bid - 1408) * 256 + t;  // over 128*256
    const int k = idx & 255;
    const int n = idx >> 8;
    float v = 0.f;
    if (n < 48) {
      const int r = n >> 3, h = (n >> 1) & 3, side = n & 1;
      const float* a = (side ? attn_r : attn_l) + r * 256 + h * 64;
      const float* wrow = W + (size_t)r * 65536 + (size_t)k * 256 + h * 64;
#pragma unroll 8
      for (int dh = 0; dh < 64; ++dh) v = fmaf(wrow[dh], a[dh], v);
    }
    wlwr[(size_t)n * 256 + k] = f2bf(v);
  } else {
    // ---- build: single-pass fixed-slot buckets (R6-verified) ----
    const int chunk = bid - 1536;
    const int lo = chunk * BSZ;
    const int hi = (lo + BSZ < NE) ? lo + BSZ : NE;
    for (int r = 0; r < NR; ++r) {
      for (int i = lo + t; i < hi; i += 256) {
        const int s = src[(size_t)r * NE + i];
        const int d = dst[(size_t)r * NE + i];
        const int g = r * NN + d;
        const int sl = atomicAdd(&deg[g], 1);
        if (sl < SLOTS)
          slots[(size_t)g * SLOTS + sl] = (unsigned short)s;
      }
    }
  }
}

// ---------------- el/er skinny MFMA GEMM: xb @ wlwr^T ---------------------
__global__ __launch_bounds__(256) void eler_kernel(
    const short* __restrict__ xb, const short* __restrict__ wlwr,
    float* __restrict__ el_all, float* __restrict__ er_all) {
  __shared__ short As[128 * 64];
  __shared__ short Bs[128 * 64];
  const int t = threadIdx.x;
  const int lane = t & 63;
  const int w = t >> 6;
  const int wm = w & 1, wn = w >> 1;
  const int row0 = blockIdx.x * 128;

  f32x4 acc[4][4];
#pragma unroll
  for (int mi = 0; mi < 4; ++mi)
#pragma unroll
    for (int ni = 0; ni < 4; ++ni) {
      f32x4 z = {0.f, 0.f, 0.f, 0.f};
      acc[mi][ni] = z;
    }

  const short* ag[4];
  const short* bg[4];
  short* la[4];
  short* lb[4];
#pragma unroll
  for (int i = 0; i < 4; ++i) {
    const int c = t + 256 * i;
    const int row = c >> 3;
    const int sslot = (c & 7) ^ (row & 7);
    int ar = row0 + row; if (ar >= NN) ar = NN - 1;
    ag[i] = xb + (size_t)ar * 256 + sslot * 8;
    bg[i] = wlwr + (size_t)row * 256 + sslot * 8;
    la[i] = As + c * 8;
    lb[i] = Bs + c * 8;
  }

  const int ra = lane & 15;
  const int qg = lane >> 4;

  for (int k0 = 0; k0 < 256; k0 += 64) {
#pragma unroll
    for (int i = 0; i < 4; ++i) {
      GLOAD_LDS16(ag[i] + k0, la[i]);
      GLOAD_LDS16(bg[i] + k0, lb[i]);
    }
    __syncthreads();
#pragma unroll
    for (int kk = 0; kk < 2; ++kk) {
      bf16x8 af[4], bfr[4];
#pragma unroll
      for (int mi = 0; mi < 4; ++mi) {
        const int rw = wm * 64 + mi * 16 + ra;
        const int ch = (kk * 4 + qg) ^ (rw & 7);
        af[mi] = *(const bf16x8*)&As[rw * 64 + ch * 8];
      }
#pragma unroll
      for (int ni = 0; ni < 4; ++ni) {
        const int rw = wn * 64 + ni * 16 + ra;
        const int ch = (kk * 4 + qg) ^ (rw & 7);
        bfr[ni] = *(const bf16x8*)&Bs[rw * 64 + ch * 8];
      }
#pragma unroll
      for (int mi = 0; mi < 4; ++mi)
#pragma unroll
        for (int ni = 0; ni < 4; ++ni)
          acc[mi][ni] = __builtin_amdgcn_mfma_f32_16x16x32_bf16(
              af[mi], bfr[ni], acc[mi][ni], 0, 0, 0);
    }
    __syncthreads();
  }

#pragma unroll
  for (int mi = 0; mi < 4; ++mi) {
#pragma unroll
    for (int j = 0; j < 4; ++j) {
      const int row = row0 + wm * 64 + mi * 16 + (lane >> 4) * 4 + j;
      if (row >= NN) continue;
#pragma unroll
      for (int ni = 0; ni < 4; ++ni) {
        const int c = wn * 64 + ni * 16 + ra;
        if (c < 48) {
          const int r = c >> 3, h = (c >> 1) & 3, side = c & 1;
          float* dstp = (side ? er_all : el_all);
          dstp[((size_t)r * NN + row) * NH + h] = acc[mi][ni][j];
        }
      }
    }
  }
}

// ---------------- bf16 MFMA GEMM (all relations) -> featb -----------------
// R6-verified BK=64 swizzled structure, grid (391,2,NR) = 4692 blocks.
// (R8's A-resident variant: 782 blocks @ 2/CU = 1.53 scheduling rounds,
// ~33% quantization tail -> +39us regression. Reverted.)
__global__ __launch_bounds__(256) void gemm_kernel(
    const short* __restrict__ xb,       // [NN][256] bf16
    const short* __restrict__ wt_all,   // [NR][256 n][256 k] bf16
    short* __restrict__ featb_all) {    // [NR][MP][256] bf16
  __shared__ short As[128 * 64];
  __shared__ short Bs[128 * 64];
  const int t = threadIdx.x;
  const int lane = t & 63;
  const int w = t >> 6;
  const int wm = w & 1, wn = w >> 1;
  const int row0 = blockIdx.x * 128;
  const int n0 = blockIdx.y * 128;
  const int r = blockIdx.z;
  const short* wt = wt_all + (size_t)r * 65536;
  short* featb = featb_all + (size_t)r * MP * 256;

  f32x4 acc[4][4];
#pragma unroll
  for (int mi = 0; mi < 4; ++mi)
#pragma unroll
    for (int ni = 0; ni < 4; ++ni) {
      f32x4 z = {0.f, 0.f, 0.f, 0.f};
      acc[mi][ni] = z;
    }

  const short* ag[4];
  const short* bg[4];
  short* la[4];
  short* lb[4];
#pragma unroll
  for (int i = 0; i < 4; ++i) {
    const int c = t + 256 * i;
    const int row = c >> 3;
    const int sslot = (c & 7) ^ (row & 7);
    int ar = row0 + row; if (ar >= NN) ar = NN - 1;
    ag[i] = xb + (size_t)ar * 256 + sslot * 8;
    bg[i] = wt + (size_t)(n0 + row) * 256 + sslot * 8;
    la[i] = As + c * 8;
    lb[i] = Bs + c * 8;
  }

  const int ra = lane & 15;
  const int qg = lane >> 4;

  for (int k0 = 0; k0 < 256; k0 += 64) {
#pragma unroll
    for (int i = 0; i < 4; ++i) {
      GLOAD_LDS16(ag[i] + k0, la[i]);
      GLOAD_LDS16(bg[i] + k0, lb[i]);
    }
    __syncthreads();
#pragma unroll
    for (int kk = 0; kk < 2; ++kk) {
      bf16x8 af[4], bfr[4];
#pragma unroll
      for (int mi = 0; mi < 4; ++mi) {
        const int rw = wm * 64 + mi * 16 + ra;
        const int ch = (kk * 4 + qg) ^ (rw & 7);
        af[mi] = *(const bf16x8*)&As[rw * 64 + ch * 8];
      }
#pragma unroll
      for (int ni = 0; ni < 4; ++ni) {
        const int rw = wn * 64 + ni * 16 + ra;
        const int ch = (kk * 4 + qg) ^ (rw & 7);
        bfr[ni] = *(const bf16x8*)&Bs[rw * 64 + ch * 8];
      }
#pragma unroll
      for (int mi = 0; mi < 4; ++mi)
#pragma unroll
        for (int ni = 0; ni < 4; ++ni)
          acc[mi][ni] = __builtin_amdgcn_mfma_f32_16x16x32_bf16(
              af[mi], bfr[ni], acc[mi][ni], 0, 0, 0);
    }
    __syncthreads();
  }

#pragma unroll
  for (int mi = 0; mi < 4; ++mi) {
#pragma unroll
    for (int j = 0; j < 4; ++j) {
      const int row = row0 + wm * 64 + mi * 16 + (lane >> 4) * 4 + j;
#pragma unroll
      for (int ni = 0; ni < 4; ++ni)
        featb[(size_t)row * 256 + n0 + wn * 64 + ni * 16 + ra] =
            f2bf(acc[mi][ni][j]);
    }
  }
}

// ---------------- fused all-relation aggregation, SGPR slot list ----------
// CONTROL math (R6-verified, random-gather BW-bound ~163us/563MB). Split
// into two half-node launches (base param) purely for PROFILING REVEAL:
// top-5 is monopolized by the slowest dispatch (R7: scan@404 filled all 5
// slots); halving agg to ~82us exposes gemm's true duration/counters.
__global__ __launch_bounds__(256) void agg_kernel(
    const short* __restrict__ featb_all, const float* __restrict__ el_all,
    const float* __restrict__ er_all, const int* __restrict__ deg,
    const unsigned short* __restrict__ slots, const float* __restrict__ bias,
    float* __restrict__ out, int base) {
  const int wid = base + ((blockIdx.x * 256 + threadIdx.x) >> 6);
  const int lane = threadIdx.x & 63;
  if (wid >= NN) return;
  const int h = lane >> 4;   // 16 lanes per head (64 cols / 4 per lane)
  const int c0 = lane * 4;   // this lane's 4 columns

  float oacc[4] = {0.f, 0.f, 0.f, 0.f};
  const int wid_u = __builtin_amdgcn_readfirstlane(wid);

  const int g_first = (NR - 1) * NN + wid_u;
  const uint4* spf = (const uint4*)(slots + (size_t)g_first * SLOTS);
  uint4 sq0 = spf[0], sq1 = spf[1], sq2 = spf[2], sq3 = spf[3];
  int dgv = deg[g_first];
  float erv = er_all[(size_t)g_first * NH + h];

  for (int r = NR - 1; r >= 0; --r) {
    const int dg0 = __builtin_amdgcn_readfirstlane(dgv);
    const int dg = dg0 > SLOTS ? SLOTS : dg0;
    unsigned sdv[16];
    sdv[0]  = __builtin_amdgcn_readfirstlane(sq0.x);
    sdv[1]  = __builtin_amdgcn_readfirstlane(sq0.y);
    sdv[2]  = __builtin_amdgcn_readfirstlane(sq0.z);
    sdv[3]  = __builtin_amdgcn_readfirstlane(sq0.w);
    sdv[4]  = __builtin_amdgcn_readfirstlane(sq1.x);
    sdv[5]  = __builtin_amdgcn_readfirstlane(sq1.y);
    sdv[6]  = __builtin_amdgcn_readfirstlane(sq1.z);
    sdv[7]  = __builtin_amdgcn_readfirstlane(sq1.w);
    sdv[8]  = __builtin_amdgcn_readfirstlane(sq2.x);
    sdv[9]  = __builtin_amdgcn_readfirstlane(sq2.y);
    sdv[10] = __builtin_amdgcn_readfirstlane(sq2.z);
    sdv[11] = __builtin_amdgcn_readfirstlane(sq2.w);
    sdv[12] = __builtin_amdgcn_readfirstlane(sq3.x);
    sdv[13] = __builtin_amdgcn_readfirstlane(sq3.y);
    sdv[14] = __builtin_amdgcn_readfirstlane(sq3.z);
    sdv[15] = __builtin_amdgcn_readfirstlane(sq3.w);
    const float er_nh = erv;

    if (r > 0) {
      const int g2 = (r - 1) * NN + wid_u;
      const uint4* sp2 = (const uint4*)(slots + (size_t)g2 * SLOTS);
      sq0 = sp2[0]; sq1 = sp2[1]; sq2 = sp2[2]; sq3 = sp2[3];
      dgv = deg[g2];
      erv = er_all[(size_t)g2 * NH + h];
    }

    const float* elr = el_all + (size_t)r * NN * NH;
    const short* fb = featb_all + (size_t)r * MP * 256;

    float z = 0.f;
    float acc[4] = {0.f, 0.f, 0.f, 0.f};

#pragma unroll
    for (int j0 = 0; j0 < SLOTS; j0 += 8) {
      if (j0 >= dg) break;  // uniform (dg is SGPR)
      float pv[8];
      uint2 rw[8];
#pragma unroll
      for (int k = 0; k < 8; ++k) {
        const int e = j0 + k;  // compile-time after unroll
        int s = (int)((e & 1) ? (sdv[e >> 1] >> 16) : (sdv[e >> 1] & 0xffffu));
        const bool v = e < dg;           // uniform
        s = v ? s : 0;                   // row 0 stays hot
        rw[k] = *(const uint2*)(fb + (size_t)s * 256 + c0);  // SGPR base+voff
        float ev = elr[s * NH + h] + er_nh;
        ev = fmaxf(ev, 0.2f * ev);       // leaky_relu(0.2)
        pv[k] = v ? __expf(ev) : 0.f;
      }
#pragma unroll
      for (int k = 0; k < 8; ++k) {
        z += pv[k];
        acc[0] = fmaf(pv[k], bf2f_lo(rw[k].x), acc[0]);
        acc[1] = fmaf(pv[k], bf2f_hi(rw[k].x), acc[1]);
        acc[2] = fmaf(pv[k], bf2f_lo(rw[k].y), acc[2]);
        acc[3] = fmaf(pv[k], bf2f_hi(rw[k].y), acc[3]);
      }
    }

    const float inv = 1.f / fmaxf(z, 1e-9f);
    const float4 bv = *(const float4*)(bias + r * HD + c0);
    oacc[0] += fmaxf(fmaf(acc[0], inv, bv.x), 0.f);
    oacc[1] += fmaxf(fmaf(acc[1], inv, bv.y), 0.f);
    oacc[2] += fmaxf(fmaf(acc[2], inv, bv.z), 0.f);
    oacc[3] += fmaxf(fmaf(acc[3], inv, bv.w), 0.f);
  }

  float4 o4 = {oacc[0], oacc[1], oacc[2], oacc[3]};
  *(float4*)(out + (size_t)wid * 256 + c0) = o4;  // full-wave 1KB store
}

// ---------------------------------------------------------------------------
extern "C" void kernel_launch(void* const* d_in, const int* in_sizes, int n_in,
                              void* d_out, int out_size, void* d_ws,
                              size_t ws_size, hipStream_t stream) {
  const float* x      = (const float*)d_in[0];
  const float* W      = (const float*)d_in[1];
  const float* attn_l = (const float*)d_in[2];
  const float* attn_r = (const float*)d_in[3];
  const float* bias   = (const float*)d_in[4];
  const int*   src    = (const int*)d_in[5];   // int32 per harness contract
  const int*   dst    = (const int*)d_in[6];
  float* out = (float*)d_out;

  char* p = (char*)d_ws;
  auto alloc = [&](size_t bytes) {
    char* r = p;
    p += (bytes + 255) & ~(size_t)255;
    return r;
  };
  short* xb    = (short*)alloc((size_t)NN * HD * 2);            // 25.6 MB
  short* wt    = (short*)alloc((size_t)NR * 256 * 256 * 2);     // 0.79 MB
  short* wlwr  = (short*)alloc((size_t)128 * 256 * 2);          // 64 KB
  short* featb = (short*)alloc((size_t)NR * MP * 256 * 2);      // 153.7 MB
  float* el    = (float*)alloc((size_t)NR * NN * NH * 4);       // 4.8 MB
  float* er    = (float*)alloc((size_t)NR * NN * NH * 4);       // 4.8 MB
  int*   deg   = (int*)alloc((size_t)NR * NN * 4);              // 1.2 MB
  unsigned short* slots =
      (unsigned short*)alloc((size_t)NR * NN * SLOTS * 2);      // 19.2 MB

  hipMemsetAsync(deg, 0, (size_t)NR * NN * 4, stream);

  prep_kernel<<<2048, 256, 0, stream>>>(x, xb, W, wt, attn_l, attn_r, wlwr,
                                        src, dst, deg, slots);
  eler_kernel<<<MP / 128, 256, 0, stream>>>(xb, wlwr, el, er);
  gemm_kernel<<<dim3(MP / 128, 2, NR), 256, 0, stream>>>(xb, wt, featb);
  agg_kernel<<<6250, 256, 0, stream>>>(featb, el, er, deg, slots, bias, out,
                                       0);
  agg_kernel<<<6250, 256, 0, stream>>>(featb, el, er, deg, slots, bias, out,
                                       25000);
}